// Round 1
// baseline (108.585 us; speedup 1.0000x reference)
//
#include <hip/hip_runtime.h>

typedef __attribute__((ext_vector_type(8))) short short8;
typedef __attribute__((ext_vector_type(4))) float f32x4;

#define T_DIM 4096
#define C_DIM 128
#define U_DIM 256
#define BM 128
#define NROWS 130   // BM + 2 halo rows
#define LDK 136     // padded LDS row stride (bf16 elems): +16B keeps ds_read_b128 even

__device__ __forceinline__ unsigned short f2bf(float f) {
    unsigned int u = __float_as_uint(f);
    u += 0x7FFFu + ((u >> 16) & 1u);   // round-to-nearest-even
    return (unsigned short)(u >> 16);
}

// Pre-pack w into MFMA B-fragment order: wfrag[ks][nt][lane][8] bf16,
// where k = ks*32 + (lane>>4)*8 + j, n = nt*16 + (lane&15).
// Also compute winv[u] = 1/(||w_col||+q^2), p2[u] = p[u]^2, copy b.
__global__ void prep_kernel(const float* __restrict__ w,
                            const float* __restrict__ b,
                            const float* __restrict__ p,
                            const float* __restrict__ q,
                            unsigned short* __restrict__ wfrag,
                            float* __restrict__ winv,
                            float* __restrict__ p2,
                            float* __restrict__ bc) {
    if (blockIdx.x < 48) {
        int idx = blockIdx.x * 256 + threadIdx.x;   // 0..12287 lane-frags
        int l  = idx & 63;
        int nt = (idx >> 6) & 15;
        int ks = idx >> 10;                         // 0..11
        int n  = nt * 16 + (l & 15);
        int k0 = ks * 32 + ((l >> 4) << 3);
        #pragma unroll
        for (int j = 0; j < 8; ++j) {
            wfrag[(size_t)idx * 8 + j] = f2bf(w[(k0 + j) * U_DIM + n]);
        }
    } else {
        int u = threadIdx.x;                        // 0..255
        float ss = 0.f;
        for (int k = 0; k < 3 * C_DIM; ++k) {
            float v = w[k * U_DIM + u];
            ss += v * v;
        }
        float q2 = q[0] * q[0];
        winv[u] = 1.0f / (sqrtf(fmaxf(ss, 1e-12f)) + q2);
        float pv = p[u];
        p2[u] = pv * pv;
        bc[u] = b[u];
    }
}

__global__ __launch_bounds__(512) void cossim_main(
        const float* __restrict__ inp,
        const unsigned short* __restrict__ wfrag,
        const float* __restrict__ winv,
        const float* __restrict__ p2g,
        const float* __restrict__ bg,
        const float* __restrict__ qg,
        float* __restrict__ out) {
    __shared__ unsigned short inp_s[NROWS][LDK];
    __shared__ float ss_s[NROWS];
    __shared__ float xninv_s[BM];

    const int tid  = threadIdx.x;
    const int bidx = blockIdx.x;
    const int bb   = bidx >> 5;          // batch index (32 tiles per batch)
    const int t0   = (bidx & 31) * BM;   // tile start within batch

    // ---- Stage 130 input rows (t0-1 .. t0+128) as bf16; f32 sumsq per row ----
    {
        const int r0 = tid >> 5;         // 0..15
        const int lc = (tid & 31) * 4;   // float column
        for (int r = r0; r < NROWS; r += 16) {
            int t = t0 + r - 1;
            float4 v = make_float4(0.f, 0.f, 0.f, 0.f);
            if (t >= 0 && t < T_DIM) {
                v = *(const float4*)(inp + ((size_t)bb * T_DIM + t) * C_DIM + lc);
            }
            float part = v.x * v.x + v.y * v.y + v.z * v.z + v.w * v.w;
            #pragma unroll
            for (int o = 16; o > 0; o >>= 1) part += __shfl_xor(part, o, 32);
            if ((tid & 31) == 0) ss_s[r] = part;
            ushort4 sv;
            sv.x = f2bf(v.x); sv.y = f2bf(v.y); sv.z = f2bf(v.z); sv.w = f2bf(v.w);
            *(ushort4*)(&inp_s[r][lc]) = sv;
        }
    }
    __syncthreads();
    if (tid < BM) {
        float s3 = ss_s[tid] + ss_s[tid + 1] + ss_s[tid + 2];
        float q2 = qg[0] * qg[0];
        xninv_s[tid] = 1.0f / (sqrtf(fmaxf(s3, 1e-12f)) + q2);
    }
    __syncthreads();

    // ---- MFMA: 8 waves as 2(M) x 4(N); each wave 64x64 = 4x4 fragments ----
    const int wid = tid >> 6;
    const int l   = tid & 63;
    const int wr  = wid >> 2;        // 0..1
    const int wc  = wid & 3;         // 0..3
    const int m0  = wr * 64;
    const int n0  = wc * 64;
    const int l15 = l & 15;
    const int lg  = l >> 4;          // 0..3
    const int nt0 = n0 >> 4;

    f32x4 acc[4][4];
    #pragma unroll
    for (int mf = 0; mf < 4; ++mf)
        #pragma unroll
        for (int nf = 0; nf < 4; ++nf)
            acc[mf][nf] = (f32x4){0.f, 0.f, 0.f, 0.f};

    const short8* wf = (const short8*)wfrag;

    for (int ks = 0; ks < 12; ++ks) {
        const int tap = ks >> 2;                    // which of the 3 taps
        const int c0  = (ks & 3) * 32 + lg * 8;     // bf16 column within tap
        short8 a[4], bfr[4];
        #pragma unroll
        for (int mf = 0; mf < 4; ++mf) {
            int row = m0 + mf * 16 + l15 + tap;     // halo-shifted LDS row
            a[mf] = *(const short8*)(&inp_s[row][c0]);
        }
        #pragma unroll
        for (int nf = 0; nf < 4; ++nf) {
            bfr[nf] = wf[(size_t)(ks * 16 + nt0 + nf) * 64 + l];
        }
        #pragma unroll
        for (int mf = 0; mf < 4; ++mf)
            #pragma unroll
            for (int nf = 0; nf < 4; ++nf)
                acc[mf][nf] = __builtin_amdgcn_mfma_f32_16x16x32_bf16(
                    a[mf], bfr[nf], acc[mf][nf], 0, 0, 0);
    }

    // ---- Epilogue: y = raw*xi*wi; out = sign(raw)*(|y|+eps)^(p^2) + b ----
    float wi[4], pp[4], bb4[4];
    #pragma unroll
    for (int nf = 0; nf < 4; ++nf) {
        int col = n0 + nf * 16 + l15;
        wi[nf]  = winv[col];
        pp[nf]  = p2g[col];
        bb4[nf] = bg[col];
    }

    #pragma unroll
    for (int mf = 0; mf < 4; ++mf) {
        #pragma unroll
        for (int j = 0; j < 4; ++j) {
            int row = m0 + mf * 16 + lg * 4 + j;    // C/D: row=(lane>>4)*4+reg
            float xi = xninv_s[row];
            float* orow = out + ((size_t)bb * T_DIM + t0 + row) * U_DIM;
            #pragma unroll
            for (int nf = 0; nf < 4; ++nf) {
                float raw = acc[mf][nf][j];
                float y   = raw * xi * wi[nf];
                float ay  = fabsf(y) + 1e-12f;
                float pw  = pp[nf];
                float rr  = (pw == 1.0f) ? ay : powf(ay, pw);
                float s   = (raw > 0.f) ? 1.f : ((raw < 0.f) ? -1.f : 0.f);
                int col   = n0 + nf * 16 + l15;     // C/D: col=lane&15
                orow[col] = s * rr + bb4[nf];
            }
        }
    }
}

extern "C" void kernel_launch(void* const* d_in, const int* in_sizes, int n_in,
                              void* d_out, int out_size, void* d_ws, size_t ws_size,
                              hipStream_t stream) {
    const float* inp = (const float*)d_in[0];
    const float* w   = (const float*)d_in[1];
    const float* b   = (const float*)d_in[2];
    const float* p   = (const float*)d_in[3];
    const float* q   = (const float*)d_in[4];
    float* out = (float*)d_out;

    unsigned short* wfrag = (unsigned short*)d_ws;            // 12*16*64*8 bf16 = 196608 B
    float* winv = (float*)((char*)d_ws + 196608);
    float* p2   = winv + 256;
    float* bc   = p2 + 256;

    prep_kernel<<<49, 256, 0, stream>>>(w, b, p, q, wfrag, winv, p2, bc);
    cossim_main<<<1024, 512, 0, stream>>>(inp, wfrag, winv, p2, bc, q, out);
}

// Round 2
// 75.817 us; speedup vs baseline: 1.4322x; 1.4322x over previous
//
#include <hip/hip_runtime.h>

typedef __attribute__((ext_vector_type(8))) short short8;
typedef __attribute__((ext_vector_type(4))) float f32x4;

#define T_DIM 4096
#define C_DIM 128
#define U_DIM 256
#define BM 128
#define NROWS 130   // BM + 2 halo rows
#define LDK 136     // padded LDS row stride (bf16 elems)

__device__ __forceinline__ unsigned short f2bf(float f) {
    unsigned int u = __float_as_uint(f);
    u += 0x7FFFu + ((u >> 16) & 1u);   // round-to-nearest-even
    return (unsigned short)(u >> 16);
}

// Pre-pack w into MFMA fragment order: wfrag[ks][nt][lane][8] bf16,
// where k = ks*32 + (lane>>4)*8 + j, u = nt*16 + (lane&15).
// Also winv[u] = 1/(||w_col||+q^2), p2[u] = p[u]^2, copy b.
__global__ void prep_kernel(const float* __restrict__ w,
                            const float* __restrict__ b,
                            const float* __restrict__ p,
                            const float* __restrict__ q,
                            unsigned short* __restrict__ wfrag,
                            float* __restrict__ winv,
                            float* __restrict__ p2,
                            float* __restrict__ bc) {
    if (blockIdx.x < 48) {
        int idx = blockIdx.x * 256 + threadIdx.x;   // 0..12287 lane-frags
        int l  = idx & 63;
        int nt = (idx >> 6) & 15;
        int ks = idx >> 10;                         // 0..11
        int n  = nt * 16 + (l & 15);
        int k0 = ks * 32 + ((l >> 4) << 3);
        #pragma unroll
        for (int j = 0; j < 8; ++j) {
            wfrag[(size_t)idx * 8 + j] = f2bf(w[(k0 + j) * U_DIM + n]);
        }
    } else {
        int u = threadIdx.x;                        // 0..255
        float ss = 0.f;
        for (int k = 0; k < 3 * C_DIM; ++k) {
            float v = w[k * U_DIM + u];
            ss += v * v;
        }
        float q2 = q[0] * q[0];
        winv[u] = 1.0f / (sqrtf(fmaxf(ss, 1e-12f)) + q2);
        float pv = p[u];
        p2[u] = pv * pv;
        bc[u] = b[u];
    }
}

__global__ __launch_bounds__(512, 4) void cossim_main(
        const float* __restrict__ inp,
        const unsigned short* __restrict__ wfrag,
        const float* __restrict__ winv,
        const float* __restrict__ p2g,
        const float* __restrict__ bg,
        const float* __restrict__ qg,
        float* __restrict__ out) {
    __shared__ unsigned short inp_s[NROWS][LDK];
    __shared__ float ss_s[NROWS];
    __shared__ float xninv_s[BM];

    const int tid  = threadIdx.x;
    const int bidx = blockIdx.x;
    const int bb   = bidx >> 5;          // batch index (32 tiles per batch)
    const int t0   = (bidx & 31) * BM;   // tile start within batch

    // ---- Stage 130 input rows (t0-1 .. t0+128) as bf16; f32 sumsq per row ----
    {
        const int r0 = tid >> 5;         // 0..15
        const int lc = (tid & 31) * 4;   // float column
        for (int r = r0; r < NROWS; r += 16) {
            int t = t0 + r - 1;
            float4 v = make_float4(0.f, 0.f, 0.f, 0.f);
            if (t >= 0 && t < T_DIM) {
                v = *(const float4*)(inp + ((size_t)bb * T_DIM + t) * C_DIM + lc);
            }
            float part = v.x * v.x + v.y * v.y + v.z * v.z + v.w * v.w;
            #pragma unroll
            for (int o = 16; o > 0; o >>= 1) part += __shfl_xor(part, o, 32);
            if ((tid & 31) == 0) ss_s[r] = part;
            ushort4 sv;
            sv.x = f2bf(v.x); sv.y = f2bf(v.y); sv.z = f2bf(v.z); sv.w = f2bf(v.w);
            *(ushort4*)(&inp_s[r][lc]) = sv;
        }
    }
    __syncthreads();
    if (tid < BM) {
        float s3 = ss_s[tid] + ss_s[tid + 1] + ss_s[tid + 2];
        float q2 = qg[0] * qg[0];
        xninv_s[tid] = 1.0f / (sqrtf(fmaxf(s3, 1e-12f)) + q2);
    }
    __syncthreads();

    // ---- MFMA: 8 waves as 2(T) x 4(U); each wave 64(t) x 64(u) ----
    // Operand swap: A = w fragment (m -> u), B = x fragment (n -> t).
    // D[u][t]: C/D layout col = lane&15 -> t, row = (lane>>4)*4 + j -> u.
    const int wid = tid >> 6;
    const int l   = tid & 63;
    const int tw  = wid >> 2;        // 0..1 (t 64-row half)
    const int uw  = wid & 3;         // 0..3 (u 64-col quarter)
    const int l15 = l & 15;
    const int lg  = l >> 4;          // 0..3

    f32x4 acc[4][4];                 // [tf][uf]
    #pragma unroll
    for (int tf = 0; tf < 4; ++tf)
        #pragma unroll
        for (int uf = 0; uf < 4; ++uf)
            acc[tf][uf] = (f32x4){0.f, 0.f, 0.f, 0.f};

    const short8* wf = (const short8*)wfrag;

    for (int ks = 0; ks < 12; ++ks) {
        const int tap = ks >> 2;                    // which of the 3 taps
        const int c0  = (ks & 3) * 32 + lg * 8;     // bf16 column within tap
        short8 xv[4], wv[4];
        #pragma unroll
        for (int tf = 0; tf < 4; ++tf) {
            int row = tw * 64 + tf * 16 + l15 + tap;   // halo-shifted LDS row
            xv[tf] = *(const short8*)(&inp_s[row][c0]);
        }
        #pragma unroll
        for (int uf = 0; uf < 4; ++uf) {
            wv[uf] = wf[(size_t)(ks * 16 + uw * 4 + uf) * 64 + l];
        }
        #pragma unroll
        for (int tf = 0; tf < 4; ++tf)
            #pragma unroll
            for (int uf = 0; uf < 4; ++uf)
                acc[tf][uf] = __builtin_amdgcn_mfma_f32_16x16x32_bf16(
                    wv[uf], xv[tf], acc[tf][uf], 0, 0, 0);
    }

    // ---- Epilogue: lane holds 4 consecutive u at fixed t -> dwordx4 stores ----
    #pragma unroll
    for (int tf = 0; tf < 4; ++tf) {
        int trow = tw * 64 + tf * 16 + l15;
        float xi = xninv_s[trow];
        float* orow = out + ((size_t)bb * T_DIM + t0 + trow) * U_DIM;
        #pragma unroll
        for (int uf = 0; uf < 4; ++uf) {
            int uc = uw * 64 + uf * 16 + lg * 4;
            f32x4 wiv = *(const f32x4*)(winv + uc);
            f32x4 ppv = *(const f32x4*)(p2g + uc);
            f32x4 bbv = *(const f32x4*)(bg + uc);
            f32x4 r;
            #pragma unroll
            for (int j = 0; j < 4; ++j) {
                float raw = acc[tf][uf][j];
                float y   = raw * xi * wiv[j];
                float ay  = fabsf(y) + 1e-12f;
                float pw  = ppv[j];
                float rr  = (pw == 1.0f) ? ay : powf(ay, pw);
                float s   = (raw > 0.f) ? 1.f : ((raw < 0.f) ? -1.f : 0.f);
                r[j] = s * rr + bbv[j];
            }
            *(f32x4*)(orow + uc) = r;
        }
    }
}

extern "C" void kernel_launch(void* const* d_in, const int* in_sizes, int n_in,
                              void* d_out, int out_size, void* d_ws, size_t ws_size,
                              hipStream_t stream) {
    const float* inp = (const float*)d_in[0];
    const float* w   = (const float*)d_in[1];
    const float* b   = (const float*)d_in[2];
    const float* p   = (const float*)d_in[3];
    const float* q   = (const float*)d_in[4];
    float* out = (float*)d_out;

    unsigned short* wfrag = (unsigned short*)d_ws;            // 12*16*64*8 bf16 = 196608 B
    float* winv = (float*)((char*)d_ws + 196608);
    float* p2   = winv + 256;
    float* bc   = p2 + 256;

    prep_kernel<<<49, 256, 0, stream>>>(w, b, p, q, wfrag, winv, p2, bc);
    cossim_main<<<1024, 512, 0, stream>>>(inp, wfrag, winv, p2, bc, q, out);
}

// Round 3
// 74.014 us; speedup vs baseline: 1.4671x; 1.0244x over previous
//
#include <hip/hip_runtime.h>

typedef __attribute__((ext_vector_type(8))) short short8;
typedef __attribute__((ext_vector_type(4))) float f32x4;

#define T_DIM 4096
#define C_DIM 128
#define U_DIM 256
#define BM 128
#define NROWS 130   // BM + 2 halo rows
#define LDK 136     // padded LDS row stride (bf16 elems)

__device__ __forceinline__ unsigned short f2bf(float f) {
    unsigned int u = __float_as_uint(f);
    u += 0x7FFFu + ((u >> 16) & 1u);   // round-to-nearest-even
    return (unsigned short)(u >> 16);
}

// Pre-pack w into MFMA fragment order: wfrag[ks][nt][lane][8] bf16,
// where k = ks*32 + (lane>>4)*8 + j, u = nt*16 + (lane&15).
// Also winv[u] = 1/(||w_col||+q^2), p2[u] = p[u]^2, copy b.
__global__ void prep_kernel(const float* __restrict__ w,
                            const float* __restrict__ b,
                            const float* __restrict__ p,
                            const float* __restrict__ q,
                            unsigned short* __restrict__ wfrag,
                            float* __restrict__ winv,
                            float* __restrict__ p2,
                            float* __restrict__ bc) {
    if (blockIdx.x < 48) {
        int idx = blockIdx.x * 256 + threadIdx.x;   // 0..12287 lane-frags
        int l  = idx & 63;
        int nt = (idx >> 6) & 15;
        int ks = idx >> 10;                         // 0..11
        int n  = nt * 16 + (l & 15);
        int k0 = ks * 32 + ((l >> 4) << 3);
        #pragma unroll
        for (int j = 0; j < 8; ++j) {
            wfrag[(size_t)idx * 8 + j] = f2bf(w[(k0 + j) * U_DIM + n]);
        }
    } else {
        int u = threadIdx.x;                        // 0..255
        float ss = 0.f;
        for (int k = 0; k < 3 * C_DIM; ++k) {
            float v = w[k * U_DIM + u];
            ss += v * v;
        }
        float q2 = q[0] * q[0];
        winv[u] = 1.0f / (sqrtf(fmaxf(ss, 1e-12f)) + q2);
        float pv = p[u];
        p2[u] = pv * pv;
        bc[u] = b[u];
    }
}

__global__ __launch_bounds__(512, 4) void cossim_main(
        const float* __restrict__ inp,
        const unsigned short* __restrict__ wfrag,
        const float* __restrict__ winv,
        const float* __restrict__ p2g,
        const float* __restrict__ bg,
        const float* __restrict__ qg,
        float* __restrict__ out) {
    __shared__ unsigned short inp_s[NROWS][LDK];
    __shared__ float ss_s[NROWS];
    __shared__ float xninv_s[BM];

    const int tid  = threadIdx.x;
    const int bidx = blockIdx.x;
    const int bb   = bidx >> 5;          // batch index (32 tiles per batch)
    const int t0   = (bidx & 31) * BM;   // tile start within batch

    // ---- Stage 130 input rows (t0-1 .. t0+128) as bf16; f32 sumsq per row ----
    // Phase 1: issue ALL 9 independent loads (one HBM latency, not nine).
    {
        const int r0 = tid >> 5;         // 0..15
        const int lc = (tid & 31) * 4;   // float column
        float4 v[9];
        #pragma unroll
        for (int i = 0; i < 9; ++i) {
            int r = r0 + i * 16;
            int t = t0 + r - 1;
            float4 val = make_float4(0.f, 0.f, 0.f, 0.f);
            if (r < NROWS && t >= 0 && t < T_DIM) {
                val = *(const float4*)(inp + ((size_t)bb * T_DIM + t) * C_DIM + lc);
            }
            v[i] = val;
        }
        // Phase 2: reduce + convert + LDS write (chains pipeline across i).
        #pragma unroll
        for (int i = 0; i < 9; ++i) {
            int r = r0 + i * 16;
            if (r < NROWS) {
                float4 val = v[i];
                float part = val.x * val.x + val.y * val.y + val.z * val.z + val.w * val.w;
                #pragma unroll
                for (int o = 16; o > 0; o >>= 1) part += __shfl_xor(part, o, 32);
                if ((tid & 31) == 0) ss_s[r] = part;
                ushort4 sv;
                sv.x = f2bf(val.x); sv.y = f2bf(val.y);
                sv.z = f2bf(val.z); sv.w = f2bf(val.w);
                *(ushort4*)(&inp_s[r][lc]) = sv;
            }
        }
    }
    __syncthreads();
    if (tid < BM) {
        float s3 = ss_s[tid] + ss_s[tid + 1] + ss_s[tid + 2];
        float q2 = qg[0] * qg[0];
        xninv_s[tid] = 1.0f / (sqrtf(fmaxf(s3, 1e-12f)) + q2);
    }
    __syncthreads();

    // ---- MFMA: 8 waves as 2(T) x 4(U); each wave 64(t) x 64(u) ----
    // A = w fragment (m -> u), B = x fragment (n -> t).
    // D[u][t]: C/D layout col = lane&15 -> t, row = (lane>>4)*4 + j -> u.
    const int wid = tid >> 6;
    const int l   = tid & 63;
    const int tw  = wid >> 2;        // 0..1 (t 64-row half)
    const int uw  = wid & 3;         // 0..3 (u 64-col quarter)
    const int l15 = l & 15;
    const int lg  = l >> 4;          // 0..3

    f32x4 acc[4][4];                 // [tf][uf]
    #pragma unroll
    for (int tf = 0; tf < 4; ++tf)
        #pragma unroll
        for (int uf = 0; uf < 4; ++uf)
            acc[tf][uf] = (f32x4){0.f, 0.f, 0.f, 0.f};

    const short8* wf = (const short8*)wfrag;

    #pragma unroll
    for (int ks = 0; ks < 12; ++ks) {
        const int tap = ks >> 2;                    // which of the 3 taps
        const int c0  = (ks & 3) * 32 + lg * 8;     // bf16 column within tap
        short8 xv[4], wv[4];
        #pragma unroll
        for (int tf = 0; tf < 4; ++tf) {
            int row = tw * 64 + tf * 16 + l15 + tap;   // halo-shifted LDS row
            xv[tf] = *(const short8*)(&inp_s[row][c0]);
        }
        #pragma unroll
        for (int uf = 0; uf < 4; ++uf) {
            wv[uf] = wf[(size_t)(ks * 16 + uw * 4 + uf) * 64 + l];
        }
        #pragma unroll
        for (int tf = 0; tf < 4; ++tf)
            #pragma unroll
            for (int uf = 0; uf < 4; ++uf)
                acc[tf][uf] = __builtin_amdgcn_mfma_f32_16x16x32_bf16(
                    wv[uf], xv[tf], acc[tf][uf], 0, 0, 0);
    }

    // ---- Epilogue: lane holds 4 consecutive u at fixed t -> dwordx4 stores ----
    #pragma unroll
    for (int tf = 0; tf < 4; ++tf) {
        int trow = tw * 64 + tf * 16 + l15;
        float xi = xninv_s[trow];
        float* orow = out + ((size_t)bb * T_DIM + t0 + trow) * U_DIM;
        #pragma unroll
        for (int uf = 0; uf < 4; ++uf) {
            int uc = uw * 64 + uf * 16 + lg * 4;
            f32x4 wiv = *(const f32x4*)(winv + uc);
            f32x4 ppv = *(const f32x4*)(p2g + uc);
            f32x4 bbv = *(const f32x4*)(bg + uc);
            f32x4 r;
            #pragma unroll
            for (int j = 0; j < 4; ++j) {
                float raw = acc[tf][uf][j];
                float y   = raw * xi * wiv[j];
                float ay  = fabsf(y) + 1e-12f;
                float pw  = ppv[j];
                float rr  = ay;
                if (pw != 1.0f) rr = powf(ay, pw);   // branch, not select: p==1 at runtime
                float s   = (raw > 0.f) ? 1.f : ((raw < 0.f) ? -1.f : 0.f);
                r[j] = s * rr + bbv[j];
            }
            *(f32x4*)(orow + uc) = r;
        }
    }
}

extern "C" void kernel_launch(void* const* d_in, const int* in_sizes, int n_in,
                              void* d_out, int out_size, void* d_ws, size_t ws_size,
                              hipStream_t stream) {
    const float* inp = (const float*)d_in[0];
    const float* w   = (const float*)d_in[1];
    const float* b   = (const float*)d_in[2];
    const float* p   = (const float*)d_in[3];
    const float* q   = (const float*)d_in[4];
    float* out = (float*)d_out;

    unsigned short* wfrag = (unsigned short*)d_ws;            // 12*16*64*8 bf16 = 196608 B
    float* winv = (float*)((char*)d_ws + 196608);
    float* p2   = winv + 256;
    float* bc   = p2 + 256;

    prep_kernel<<<49, 256, 0, stream>>>(w, b, p, q, wfrag, winv, p2, bc);
    cossim_main<<<1024, 512, 0, stream>>>(inp, wfrag, winv, p2, bc, q, out);
}